// Round 1
// baseline (5434.521 us; speedup 1.0000x reference)
//
#include <hip/hip_runtime.h>

typedef unsigned short u16;
typedef unsigned int   u32;
typedef unsigned long long u64;
typedef __attribute__((ext_vector_type(8))) short s8v;   // 8 bf16 (4 VGPRs) MFMA operand
typedef __attribute__((ext_vector_type(4))) float f4v;   // MFMA accumulator

#define NN 20000
#define EE 320000
#define BB 128
#define HH 256

union BU { u64 d[2]; s8v v; };

__device__ __forceinline__ u16 f2bf(float f){
  u32 u = __float_as_uint(f);
  return (u16)((u + 0x7FFFu + ((u >> 16) & 1u)) >> 16);   // RNE
}
__device__ __forceinline__ u64 pack4bf(float a, float b, float c, float d){
  return (u64)f2bf(a) | ((u64)f2bf(b) << 16) | ((u64)f2bf(c) << 32) | ((u64)f2bf(d) << 48);
}
__device__ __forceinline__ float siluf(float v){ return v / (1.0f + __expf(-v)); }

// ---------------- weight packing: W [K][256] f32 -> A-fragment blob (W^T), bf16 ----------------
// frag layout: lane l holds A[m = mf*16 + (l&15)][k = kb*32 + (l>>4)*4 + j (j<4) | +16 (j>=4)]
// blob addr: ((kb*16 + mf)*64 + lane)*8 ushorts
__global__ void pack_kernel(const float* __restrict__ src, u16* __restrict__ dst, int K, int KB){
  int t = blockIdx.x * 256 + threadIdx.x;
  if (t >= KB * 1024) return;
  int lane = t & 63, mf = (t >> 6) & 15, kb = t >> 10;
  int g = lane >> 4, li = lane & 15;
  int m = mf * 16 + li;
  u16 o[8];
  #pragma unroll
  for (int j = 0; j < 8; ++j){
    int k = kb * 32 + ((j < 4) ? (g * 4 + j) : (16 + g * 4 + (j - 4)));
    o[j] = (k < K) ? f2bf(src[(size_t)k * 256 + m]) : (u16)0;
  }
  u16* d = dst + ((size_t)(kb * 16 + mf) * 64 + lane) * 8;
  *(u64*)(d)     = (u64)o[0] | ((u64)o[1] << 16) | ((u64)o[2] << 32) | ((u64)o[3] << 48);
  *(u64*)(d + 4) = (u64)o[4] | ((u64)o[5] << 16) | ((u64)o[6] << 32) | ((u64)o[7] << 48);
}

// ---------------- small utility kernels ----------------
__global__ void cnt_kernel(const int* __restrict__ ei, float* __restrict__ cnt){
  int t = blockIdx.x * 256 + threadIdx.x;
  if (t < EE) atomicAdd(&cnt[ei[t]], 1.0f);
}
__global__ void coord_init_kernel(const float* __restrict__ pos, float4* __restrict__ coord){
  int t = blockIdx.x * 256 + threadIdx.x;
  if (t < NN) coord[t] = make_float4(pos[3*t], pos[3*t+1], pos[3*t+2], 0.f);
}
__global__ void coord_upd_kernel(float4* __restrict__ coord, const float* __restrict__ cacc,
                                 const float* __restrict__ cnt){
  int t = blockIdx.x * 256 + threadIdx.x;
  if (t >= NN) return;
  float k = fmaxf(cnt[t], 1.0f);
  float4 c = coord[t];
  c.x += cacc[4*t+0] / k; c.y += cacc[4*t+1] / k; c.z += cacc[4*t+2] / k;
  coord[t] = c;
}
__global__ void pool_init_kernel(u32* __restrict__ pooled){
  int t = blockIdx.x * 256 + threadIdx.x;
  if (t < BB * HH){
    u32 u = __float_as_uint(-3.0e38f);
    pooled[t] = ~u;                       // monotone map of -3e38 (negative: ~bits)
  }
}
__global__ void build_z_kernel(const u32* __restrict__ pooled, const float* __restrict__ fragl,
                               const float* __restrict__ addf, float* __restrict__ z){
  int t = blockIdx.x * 256 + threadIdx.x;
  if (t >= BB * 272) return;
  int b = t / 272, j = t % 272;
  float v;
  if (j < 256){
    u32 u = pooled[b * 256 + j];
    v = (u & 0x80000000u) ? __uint_as_float(u & 0x7FFFFFFFu) : __uint_as_float(~u);
  } else if (j < 264) v = fragl[b * 8 + (j - 256)];
  else                v = addf[b * 8 + (j - 264)];
  z[t] = v;
}

// ---------------- emb_in: h = x @ emb_in_w + b   (transposed MFMA, K=128) ----------------
__global__ __launch_bounds__(256) void emb_in_kernel(
    const float* __restrict__ x, const u16* __restrict__ pw,
    const float* __restrict__ bias, float* __restrict__ h, u16* __restrict__ hb){
  const int tid = threadIdx.x;
  const int w = tid >> 6, l = tid & 63, g = l >> 4, li = l & 15;
  const int nb = blockIdx.x * 64;
  const float* xp[4];
  #pragma unroll
  for (int nf = 0; nf < 4; ++nf){
    int n = nb + nf * 16 + li; if (n >= NN) n = NN - 1;
    xp[nf] = x + (size_t)n * 128 + g * 4;
  }
  f4v acc[4][4];
  #pragma unroll
  for (int a = 0; a < 4; ++a)
    #pragma unroll
    for (int b = 0; b < 4; ++b) acc[a][b] = (f4v){0.f,0.f,0.f,0.f};
  const u16* pwb = pw + ((size_t)(w * 4) * 64 + l) * 8;
  for (int kb = 0; kb < 4; ++kb){
    s8v A[4];
    #pragma unroll
    for (int mf = 0; mf < 4; ++mf) A[mf] = *(const s8v*)(pwb + (size_t)kb * 8192 + mf * 512);
    #pragma unroll
    for (int nf = 0; nf < 4; ++nf){
      float4 fa = *(const float4*)(xp[nf] + kb * 32);
      float4 fb = *(const float4*)(xp[nf] + kb * 32 + 16);
      BU bu;
      bu.d[0] = pack4bf(fa.x, fa.y, fa.z, fa.w);
      bu.d[1] = pack4bf(fb.x, fb.y, fb.z, fb.w);
      #pragma unroll
      for (int mf = 0; mf < 4; ++mf)
        acc[mf][nf] = __builtin_amdgcn_mfma_f32_16x16x32_bf16(A[mf], bu.v, acc[mf][nf], 0, 0, 0);
    }
  }
  #pragma unroll
  for (int mf = 0; mf < 4; ++mf){
    const int fb = w * 64 + mf * 16 + g * 4;
    float b0 = bias[fb], b1 = bias[fb+1], b2 = bias[fb+2], b3 = bias[fb+3];
    #pragma unroll
    for (int nf = 0; nf < 4; ++nf){
      int n = nb + nf * 16 + li;
      if (n < NN){
        float o0 = acc[mf][nf][0] + b0, o1 = acc[mf][nf][1] + b1;
        float o2 = acc[mf][nf][2] + b2, o3 = acc[mf][nf][3] + b3;
        *(float4*)(h + (size_t)n * HH + fb) = make_float4(o0, o1, o2, o3);
        *(u64*)(hb + (size_t)n * HH + fb) = pack4bf(o0, o1, o2, o3);
      }
    }
  }
}

// ---------------- edge kernel: one block = 64 edges, 4 waves split 256 out-feats ----------------
__global__ __launch_bounds__(256) void edge_kernel(
    const u16* __restrict__ hb, const float4* __restrict__ coord,
    const int* __restrict__ ei, const float* __restrict__ eattr,
    const u16* __restrict__ pw1, const u16* __restrict__ pw2, const u16* __restrict__ pw3,
    const float* __restrict__ b1, const float* __restrict__ b2,
    const float* __restrict__ cb1, const float* __restrict__ cw2,
    float* __restrict__ agg, float* __restrict__ cacc){
  __shared__ u64 mt[4096];            // 32KB swizzled tile [64 edges][64 4-feat chunks]
  __shared__ float4 dif[64];          // diff.xyz, radial
  __shared__ u16 tailb[2048];         // tail K-block (radial | edge_attr | pad)
  __shared__ int rows_s[64];
  __shared__ int cols_s[64];
  __shared__ float bias_s[1024];      // b1 | b2 | cb1 | cw2
  __shared__ float cpart[4][64];

  const int tid = threadIdx.x;
  const int w = tid >> 6, l = tid & 63, g = l >> 4, li = l & 15;
  const int eb = blockIdx.x * 64;

  if (tid < 64){
    int e = eb + tid;
    int r = ei[e], c = ei[EE + e];
    rows_s[tid] = r; cols_s[tid] = c;
    float4 ca = coord[r], cb = coord[c];
    float dx = ca.x - cb.x, dy = ca.y - cb.y, dz = ca.z - cb.z;
    float rad = dx*dx + dy*dy + dz*dz;
    dif[tid] = make_float4(dx, dy, dz, rad);
    tailb[tid*32 + 0] = f2bf(rad);
    #pragma unroll
    for (int j = 0; j < 16; ++j) tailb[tid*32 + 1 + j] = f2bf(eattr[(size_t)e*16 + j]);
    #pragma unroll
    for (int j = 17; j < 32; ++j) tailb[tid*32 + j] = 0;
  }
  for (int i = tid; i < 1024; i += 256){
    float v;
    if      (i < 256) v = b1[i];
    else if (i < 512) v = b2[i - 256];
    else if (i < 768) v = cb1[i - 512];
    else              v = cw2[i - 768];
    bias_s[i] = v;
  }
  __syncthreads();

  const u16* rp[4]; const u16* cp[4];
  #pragma unroll
  for (int nf = 0; nf < 4; ++nf){
    int e = nf * 16 + li;
    rp[nf] = hb + (size_t)rows_s[e] * HH + g * 4;
    cp[nf] = hb + (size_t)cols_s[e] * HH + g * 4;
  }

  f4v acc[4][4];
  #pragma unroll
  for (int a = 0; a < 4; ++a)
    #pragma unroll
    for (int b = 0; b < 4; ++b) acc[a][b] = (f4v){0.f,0.f,0.f,0.f};

  // ---- GEMM1: m1 = silu(X @ W1 + b1), X = [h[row] | h[col] | radial | ea | 0pad], K=544
  const u16* pw1b = pw1 + ((size_t)(w * 4) * 64 + l) * 8;
  for (int kb = 0; kb < 8; ++kb){                       // k 0..255 from h[row]
    s8v A[4];
    #pragma unroll
    for (int mf = 0; mf < 4; ++mf) A[mf] = *(const s8v*)(pw1b + (size_t)kb * 8192 + mf * 512);
    #pragma unroll
    for (int nf = 0; nf < 4; ++nf){
      BU bu;
      bu.d[0] = *(const u64*)(rp[nf] + kb * 32);
      bu.d[1] = *(const u64*)(rp[nf] + kb * 32 + 16);
      #pragma unroll
      for (int mf = 0; mf < 4; ++mf)
        acc[mf][nf] = __builtin_amdgcn_mfma_f32_16x16x32_bf16(A[mf], bu.v, acc[mf][nf], 0, 0, 0);
    }
  }
  for (int kb = 8; kb < 16; ++kb){                      // k 256..511 from h[col]
    s8v A[4];
    #pragma unroll
    for (int mf = 0; mf < 4; ++mf) A[mf] = *(const s8v*)(pw1b + (size_t)kb * 8192 + mf * 512);
    #pragma unroll
    for (int nf = 0; nf < 4; ++nf){
      BU bu;
      bu.d[0] = *(const u64*)(cp[nf] + (kb - 8) * 32);
      bu.d[1] = *(const u64*)(cp[nf] + (kb - 8) * 32 + 16);
      #pragma unroll
      for (int mf = 0; mf < 4; ++mf)
        acc[mf][nf] = __builtin_amdgcn_mfma_f32_16x16x32_bf16(A[mf], bu.v, acc[mf][nf], 0, 0, 0);
    }
  }
  {                                                     // k 512..543 tail
    s8v A[4];
    #pragma unroll
    for (int mf = 0; mf < 4; ++mf) A[mf] = *(const s8v*)(pw1b + (size_t)16 * 8192 + mf * 512);
    #pragma unroll
    for (int nf = 0; nf < 4; ++nf){
      int e = nf * 16 + li;
      BU bu;
      bu.d[0] = *(const u64*)(tailb + e * 32 + g * 4);
      bu.d[1] = *(const u64*)(tailb + e * 32 + 16 + g * 4);
      #pragma unroll
      for (int mf = 0; mf < 4; ++mf)
        acc[mf][nf] = __builtin_amdgcn_mfma_f32_16x16x32_bf16(A[mf], bu.v, acc[mf][nf], 0, 0, 0);
    }
  }
  // bias + silu -> m1 tile (swizzled LDS)
  #pragma unroll
  for (int mf = 0; mf < 4; ++mf){
    const int fb = w * 64 + mf * 16 + g * 4;
    const int fc = fb >> 2;
    #pragma unroll
    for (int nf = 0; nf < 4; ++nf){
      int e = nf * 16 + li;
      float v0 = siluf(acc[mf][nf][0] + bias_s[fb+0]);
      float v1 = siluf(acc[mf][nf][1] + bias_s[fb+1]);
      float v2 = siluf(acc[mf][nf][2] + bias_s[fb+2]);
      float v3 = siluf(acc[mf][nf][3] + bias_s[fb+3]);
      mt[e * 64 + (fc ^ (e & 7))] = pack4bf(v0, v1, v2, v3);
    }
  }
  __syncthreads();

  // ---- GEMM2: m2 = silu(m1 @ W2 + b2), K=256
  #pragma unroll
  for (int a = 0; a < 4; ++a)
    #pragma unroll
    for (int b = 0; b < 4; ++b) acc[a][b] = (f4v){0.f,0.f,0.f,0.f};
  const u16* pw2b = pw2 + ((size_t)(w * 4) * 64 + l) * 8;
  for (int kb = 0; kb < 8; ++kb){
    s8v A[4];
    #pragma unroll
    for (int mf = 0; mf < 4; ++mf) A[mf] = *(const s8v*)(pw2b + (size_t)kb * 8192 + mf * 512);
    #pragma unroll
    for (int nf = 0; nf < 4; ++nf){
      int e = nf * 16 + li;
      BU bu;
      bu.d[0] = mt[e * 64 + ((kb * 8 + g)     ^ (e & 7))];
      bu.d[1] = mt[e * 64 + ((kb * 8 + 4 + g) ^ (e & 7))];
      #pragma unroll
      for (int mf = 0; mf < 4; ++mf)
        acc[mf][nf] = __builtin_amdgcn_mfma_f32_16x16x32_bf16(A[mf], bu.v, acc[mf][nf], 0, 0, 0);
    }
  }
  #pragma unroll
  for (int mf = 0; mf < 4; ++mf){
    const int fb = w * 64 + mf * 16 + g * 4;
    #pragma unroll
    for (int nf = 0; nf < 4; ++nf){
      #pragma unroll
      for (int r = 0; r < 4; ++r)
        acc[mf][nf][r] = siluf(acc[mf][nf][r] + bias_s[256 + fb + r]);
    }
  }
  __syncthreads();                       // all waves done reading m1
  // write m2 tile + scatter-add agg
  #pragma unroll
  for (int mf = 0; mf < 4; ++mf){
    const int fb = w * 64 + mf * 16 + g * 4;
    const int fc = fb >> 2;
    #pragma unroll
    for (int nf = 0; nf < 4; ++nf){
      int e = nf * 16 + li;
      mt[e * 64 + (fc ^ (e & 7))] = pack4bf(acc[mf][nf][0], acc[mf][nf][1], acc[mf][nf][2], acc[mf][nf][3]);
      float* ag = agg + (size_t)rows_s[e] * HH + fb;
      atomicAdd(ag + 0, acc[mf][nf][0]);
      atomicAdd(ag + 1, acc[mf][nf][1]);
      atomicAdd(ag + 2, acc[mf][nf][2]);
      atomicAdd(ag + 3, acc[mf][nf][3]);
    }
  }
  __syncthreads();

  // ---- GEMM3: q = silu(m2 @ CW1 + cb1); c = q . cw2
  #pragma unroll
  for (int a = 0; a < 4; ++a)
    #pragma unroll
    for (int b = 0; b < 4; ++b) acc[a][b] = (f4v){0.f,0.f,0.f,0.f};
  const u16* pw3b = pw3 + ((size_t)(w * 4) * 64 + l) * 8;
  for (int kb = 0; kb < 8; ++kb){
    s8v A[4];
    #pragma unroll
    for (int mf = 0; mf < 4; ++mf) A[mf] = *(const s8v*)(pw3b + (size_t)kb * 8192 + mf * 512);
    #pragma unroll
    for (int nf = 0; nf < 4; ++nf){
      int e = nf * 16 + li;
      BU bu;
      bu.d[0] = mt[e * 64 + ((kb * 8 + g)     ^ (e & 7))];
      bu.d[1] = mt[e * 64 + ((kb * 8 + 4 + g) ^ (e & 7))];
      #pragma unroll
      for (int mf = 0; mf < 4; ++mf)
        acc[mf][nf] = __builtin_amdgcn_mfma_f32_16x16x32_bf16(A[mf], bu.v, acc[mf][nf], 0, 0, 0);
    }
  }
  float cp4[4] = {0.f, 0.f, 0.f, 0.f};
  #pragma unroll
  for (int mf = 0; mf < 4; ++mf){
    const int fb = w * 64 + mf * 16 + g * 4;
    #pragma unroll
    for (int nf = 0; nf < 4; ++nf){
      #pragma unroll
      for (int r = 0; r < 4; ++r){
        float q = siluf(acc[mf][nf][r] + bias_s[512 + fb + r]);
        cp4[nf] += q * bias_s[768 + fb + r];
      }
    }
  }
  #pragma unroll
  for (int nf = 0; nf < 4; ++nf){
    float v = cp4[nf];
    v += __shfl_xor(v, 16, 64);
    v += __shfl_xor(v, 32, 64);
    if (g == 0) cpart[w][nf * 16 + li] = v;
  }
  __syncthreads();
  if (tid < 64){
    float c = cpart[0][tid] + cpart[1][tid] + cpart[2][tid] + cpart[3][tid];
    float4 d = dif[tid];
    int r = rows_s[tid];
    atomicAdd(cacc + (size_t)r * 4 + 0, d.x * c);
    atomicAdd(cacc + (size_t)r * 4 + 1, d.y * c);
    atomicAdd(cacc + (size_t)r * 4 + 2, d.z * c);
  }
}

// ---------------- node kernel: h += MLP([h, agg]) ----------------
__global__ __launch_bounds__(256) void node_kernel(
    float* __restrict__ h, u16* __restrict__ hb, const float* __restrict__ agg,
    const u16* __restrict__ pw1, const u16* __restrict__ pw2,
    const float* __restrict__ b1, const float* __restrict__ b2){
  __shared__ u64 mt[4096];
  __shared__ float bias_s[512];
  const int tid = threadIdx.x;
  const int w = tid >> 6, l = tid & 63, g = l >> 4, li = l & 15;
  const int nb = blockIdx.x * 64;
  for (int i = tid; i < 512; i += 256) bias_s[i] = (i < 256) ? b1[i] : b2[i - 256];
  __syncthreads();

  const u16* hp[4]; const float* ap[4];
  #pragma unroll
  for (int nf = 0; nf < 4; ++nf){
    int n = nb + nf * 16 + li; if (n >= NN) n = NN - 1;
    hp[nf] = hb  + (size_t)n * HH + g * 4;
    ap[nf] = agg + (size_t)n * HH + g * 4;
  }
  f4v acc[4][4];
  #pragma unroll
  for (int a = 0; a < 4; ++a)
    #pragma unroll
    for (int b = 0; b < 4; ++b) acc[a][b] = (f4v){0.f,0.f,0.f,0.f};

  const u16* pw1b = pw1 + ((size_t)(w * 4) * 64 + l) * 8;
  for (int kb = 0; kb < 8; ++kb){                       // k 0..255 from h (bf16)
    s8v A[4];
    #pragma unroll
    for (int mf = 0; mf < 4; ++mf) A[mf] = *(const s8v*)(pw1b + (size_t)kb * 8192 + mf * 512);
    #pragma unroll
    for (int nf = 0; nf < 4; ++nf){
      BU bu;
      bu.d[0] = *(const u64*)(hp[nf] + kb * 32);
      bu.d[1] = *(const u64*)(hp[nf] + kb * 32 + 16);
      #pragma unroll
      for (int mf = 0; mf < 4; ++mf)
        acc[mf][nf] = __builtin_amdgcn_mfma_f32_16x16x32_bf16(A[mf], bu.v, acc[mf][nf], 0, 0, 0);
    }
  }
  for (int kb = 8; kb < 16; ++kb){                      // k 256..511 from agg (f32 -> bf16)
    s8v A[4];
    #pragma unroll
    for (int mf = 0; mf < 4; ++mf) A[mf] = *(const s8v*)(pw1b + (size_t)kb * 8192 + mf * 512);
    #pragma unroll
    for (int nf = 0; nf < 4; ++nf){
      float4 fa = *(const float4*)(ap[nf] + (kb - 8) * 32);
      float4 fb = *(const float4*)(ap[nf] + (kb - 8) * 32 + 16);
      BU bu;
      bu.d[0] = pack4bf(fa.x, fa.y, fa.z, fa.w);
      bu.d[1] = pack4bf(fb.x, fb.y, fb.z, fb.w);
      #pragma unroll
      for (int mf = 0; mf < 4; ++mf)
        acc[mf][nf] = __builtin_amdgcn_mfma_f32_16x16x32_bf16(A[mf], bu.v, acc[mf][nf], 0, 0, 0);
    }
  }
  #pragma unroll
  for (int mf = 0; mf < 4; ++mf){
    const int fb = w * 64 + mf * 16 + g * 4;
    const int fc = fb >> 2;
    #pragma unroll
    for (int nf = 0; nf < 4; ++nf){
      int e = nf * 16 + li;
      float v0 = siluf(acc[mf][nf][0] + bias_s[fb+0]);
      float v1 = siluf(acc[mf][nf][1] + bias_s[fb+1]);
      float v2 = siluf(acc[mf][nf][2] + bias_s[fb+2]);
      float v3 = siluf(acc[mf][nf][3] + bias_s[fb+3]);
      mt[e * 64 + (fc ^ (e & 7))] = pack4bf(v0, v1, v2, v3);
    }
  }
  __syncthreads();

  #pragma unroll
  for (int a = 0; a < 4; ++a)
    #pragma unroll
    for (int b = 0; b < 4; ++b) acc[a][b] = (f4v){0.f,0.f,0.f,0.f};
  const u16* pw2b = pw2 + ((size_t)(w * 4) * 64 + l) * 8;
  for (int kb = 0; kb < 8; ++kb){
    s8v A[4];
    #pragma unroll
    for (int mf = 0; mf < 4; ++mf) A[mf] = *(const s8v*)(pw2b + (size_t)kb * 8192 + mf * 512);
    #pragma unroll
    for (int nf = 0; nf < 4; ++nf){
      int e = nf * 16 + li;
      BU bu;
      bu.d[0] = mt[e * 64 + ((kb * 8 + g)     ^ (e & 7))];
      bu.d[1] = mt[e * 64 + ((kb * 8 + 4 + g) ^ (e & 7))];
      #pragma unroll
      for (int mf = 0; mf < 4; ++mf)
        acc[mf][nf] = __builtin_amdgcn_mfma_f32_16x16x32_bf16(A[mf], bu.v, acc[mf][nf], 0, 0, 0);
    }
  }
  #pragma unroll
  for (int mf = 0; mf < 4; ++mf){
    const int fb = w * 64 + mf * 16 + g * 4;
    #pragma unroll
    for (int nf = 0; nf < 4; ++nf){
      int n = nb + nf * 16 + li;
      if (n < NN){
        float4 hv = *(float4*)(h + (size_t)n * HH + fb);
        float o0 = hv.x + acc[mf][nf][0] + bias_s[256+fb+0];
        float o1 = hv.y + acc[mf][nf][1] + bias_s[256+fb+1];
        float o2 = hv.z + acc[mf][nf][2] + bias_s[256+fb+2];
        float o3 = hv.w + acc[mf][nf][3] + bias_s[256+fb+3];
        *(float4*)(h + (size_t)n * HH + fb) = make_float4(o0, o1, o2, o3);
        *(u64*)(hb + (size_t)n * HH + fb) = pack4bf(o0, o1, o2, o3);
      }
    }
  }
}

// ---------------- emb_out + max-pool ----------------
__global__ __launch_bounds__(256) void emb_out_pool_kernel(
    const u16* __restrict__ hb, const u16* __restrict__ pw,
    const float* __restrict__ bias, const int* __restrict__ batch, u32* __restrict__ pooled){
  const int tid = threadIdx.x;
  const int w = tid >> 6, l = tid & 63, g = l >> 4, li = l & 15;
  const int nb = blockIdx.x * 64;
  const u16* hp[4]; int bs[4];
  #pragma unroll
  for (int nf = 0; nf < 4; ++nf){
    int n = nb + nf * 16 + li; int nc = (n >= NN) ? NN - 1 : n;
    hp[nf] = hb + (size_t)nc * HH + g * 4;
    bs[nf] = batch[nc];
  }
  f4v acc[4][4];
  #pragma unroll
  for (int a = 0; a < 4; ++a)
    #pragma unroll
    for (int b = 0; b < 4; ++b) acc[a][b] = (f4v){0.f,0.f,0.f,0.f};
  const u16* pwb = pw + ((size_t)(w * 4) * 64 + l) * 8;
  for (int kb = 0; kb < 8; ++kb){
    s8v A[4];
    #pragma unroll
    for (int mf = 0; mf < 4; ++mf) A[mf] = *(const s8v*)(pwb + (size_t)kb * 8192 + mf * 512);
    #pragma unroll
    for (int nf = 0; nf < 4; ++nf){
      BU bu;
      bu.d[0] = *(const u64*)(hp[nf] + kb * 32);
      bu.d[1] = *(const u64*)(hp[nf] + kb * 32 + 16);
      #pragma unroll
      for (int mf = 0; mf < 4; ++mf)
        acc[mf][nf] = __builtin_amdgcn_mfma_f32_16x16x32_bf16(A[mf], bu.v, acc[mf][nf], 0, 0, 0);
    }
  }
  #pragma unroll
  for (int mf = 0; mf < 4; ++mf){
    const int fb = w * 64 + mf * 16 + g * 4;
    float b0 = bias[fb], b1 = bias[fb+1], b2 = bias[fb+2], b3 = bias[fb+3];
    #pragma unroll
    for (int nf = 0; nf < 4; ++nf){
      int n = nb + nf * 16 + li;
      if (n < NN){
        float vv[4] = {acc[mf][nf][0] + b0, acc[mf][nf][1] + b1, acc[mf][nf][2] + b2, acc[mf][nf][3] + b3};
        #pragma unroll
        for (int r = 0; r < 4; ++r){
          u32 u = __float_as_uint(vv[r]);
          u = (u & 0x80000000u) ? ~u : (u | 0x80000000u);
          atomicMax(&pooled[(size_t)bs[nf] * HH + fb + r], u);
        }
      }
    }
  }
}

// ---------------- resblock + head (tiny: 128 graphs) ----------------
__global__ __launch_bounds__(256) void final_kernel(
    const float* __restrict__ z, const float* __restrict__ rw1, const float* __restrict__ rb1,
    const float* __restrict__ rw2, const float* __restrict__ rb2,
    const float* __restrict__ hw, const float* __restrict__ hbs, float* __restrict__ out){
  __shared__ float zr[272], t1[256], t2[272];
  const int b = blockIdx.x, tid = threadIdx.x;
  for (int i = tid; i < 272; i += 256) zr[i] = z[(size_t)b * 272 + i];
  __syncthreads();
  {
    float a = rb1[tid];
    for (int k = 0; k < 272; ++k) a += zr[k] * rw1[(size_t)k * 256 + tid];
    t1[tid] = siluf(a);
  }
  __syncthreads();
  for (int i = tid; i < 272; i += 256){
    float a = rb2[i] + zr[i];
    for (int k = 0; k < 256; ++k) a += t1[k] * rw2[(size_t)k * 272 + i];
    t2[i] = a;
  }
  __syncthreads();
  for (int p = tid; p < 2000; p += 256){
    float a = hbs[p];
    for (int k = 0; k < 272; ++k) a += t2[k] * hw[(size_t)k * 2000 + p];
    out[(size_t)b * 2000 + p] = a;
  }
}

extern "C" void kernel_launch(void* const* d_in, const int* in_sizes, int n_in,
                              void* d_out, int out_size, void* d_ws, size_t ws_size,
                              hipStream_t stream){
  const float* x        = (const float*)d_in[0];
  const float* pos      = (const float*)d_in[1];
  const float* eattr    = (const float*)d_in[2];
  const float* fragl    = (const float*)d_in[3];
  const float* addf     = (const float*)d_in[4];
  const int*   ei       = (const int*)d_in[5];
  const int*   batch    = (const int*)d_in[6];
  const float* emb_in_w = (const float*)d_in[7];
  const float* emb_in_b = (const float*)d_in[8];
  const float* edge_w1  = (const float*)d_in[9];
  const float* edge_b1  = (const float*)d_in[10];
  const float* edge_w2  = (const float*)d_in[11];
  const float* edge_b2  = (const float*)d_in[12];
  const float* node_w1  = (const float*)d_in[13];
  const float* node_b1  = (const float*)d_in[14];
  const float* node_w2  = (const float*)d_in[15];
  const float* node_b2  = (const float*)d_in[16];
  const float* coord_w1 = (const float*)d_in[17];
  const float* coord_b1 = (const float*)d_in[18];
  const float* coord_w2 = (const float*)d_in[19];
  const float* emb_out_w= (const float*)d_in[20];
  const float* emb_out_b= (const float*)d_in[21];
  const float* res_w1   = (const float*)d_in[22];
  const float* res_b1   = (const float*)d_in[23];
  const float* res_w2   = (const float*)d_in[24];
  const float* res_b2   = (const float*)d_in[25];
  const float* head_w   = (const float*)d_in[26];
  const float* head_b   = (const float*)d_in[27];

  char* ws = (char*)d_ws;
  size_t off = 0;
  auto alloc = [&](size_t bytes) -> void* {
    void* p = ws + off;
    off += (bytes + 255) & ~(size_t)255;
    return p;
  };
  float*  h      = (float*)alloc((size_t)NN * HH * 4);
  float*  agg    = (float*)alloc((size_t)NN * HH * 4);
  u16*    hb     = (u16*)  alloc((size_t)NN * HH * 2);
  float4* coordb = (float4*)alloc((size_t)NN * 16);
  float*  cacc   = (float*)alloc((size_t)NN * 16);
  float*  cnt    = (float*)alloc((size_t)NN * 4);
  u32*    pooled = (u32*)  alloc((size_t)BB * HH * 4);
  float*  z      = (float*)alloc((size_t)BB * 272 * 4);
  u16*    packed = (u16*)  alloc((size_t)7680 * 256 * 2);
  if (off > ws_size) return;   // workspace too small -> fail loudly (poisoned d_out)

  // packed weight sub-blobs (ushort offsets)
  u16* pk_embin  = packed;                                  // KB=4
  u16* pk_embout = packed + 32768 + (size_t)4 * 466944;     // KB=8
  auto pk_ew1 = [&](int l){ return packed + 32768 + (size_t)l * 466944; };
  auto pk_ew2 = [&](int l){ return pk_ew1(l) + 139264; };
  auto pk_cw1 = [&](int l){ return pk_ew1(l) + 204800; };
  auto pk_nw1 = [&](int l){ return pk_ew1(l) + 270336; };
  auto pk_nw2 = [&](int l){ return pk_ew1(l) + 401408; };

  // ---- pack all weights (once per launch; weights are static inputs)
  pack_kernel<<<16, 256, 0, stream>>>(emb_in_w, pk_embin, 128, 4);
  for (int l = 0; l < 4; ++l){
    pack_kernel<<<68, 256, 0, stream>>>(edge_w1 + (size_t)l * 529 * 256, pk_ew1(l), 529, 17);
    pack_kernel<<<32, 256, 0, stream>>>(edge_w2 + (size_t)l * 65536,     pk_ew2(l), 256, 8);
    pack_kernel<<<32, 256, 0, stream>>>(coord_w1 + (size_t)l * 65536,    pk_cw1(l), 256, 8);
    pack_kernel<<<64, 256, 0, stream>>>(node_w1 + (size_t)l * 131072,    pk_nw1(l), 512, 16);
    pack_kernel<<<32, 256, 0, stream>>>(node_w2 + (size_t)l * 65536,     pk_nw2(l), 256, 8);
  }
  pack_kernel<<<32, 256, 0, stream>>>(emb_out_w, pk_embout, 256, 8);

  hipMemsetAsync(cnt, 0, (size_t)NN * 4, stream);
  cnt_kernel<<<1250, 256, 0, stream>>>(ei, cnt);
  coord_init_kernel<<<79, 256, 0, stream>>>(pos, coordb);
  emb_in_kernel<<<313, 256, 0, stream>>>(x, pk_embin, emb_in_b, h, hb);

  for (int l = 0; l < 4; ++l){
    hipMemsetAsync(agg,  0, (size_t)NN * HH * 4, stream);
    hipMemsetAsync(cacc, 0, (size_t)NN * 16, stream);
    edge_kernel<<<5000, 256, 0, stream>>>(hb, coordb, ei, eattr,
        pk_ew1(l), pk_ew2(l), pk_cw1(l),
        edge_b1 + l * 256, edge_b2 + l * 256, coord_b1 + l * 256, coord_w2 + l * 256,
        agg, cacc);
    coord_upd_kernel<<<79, 256, 0, stream>>>(coordb, cacc, cnt);
    node_kernel<<<313, 256, 0, stream>>>(h, hb, agg, pk_nw1(l), pk_nw2(l),
        node_b1 + l * 256, node_b2 + l * 256);
  }

  pool_init_kernel<<<128, 256, 0, stream>>>(pooled);
  emb_out_pool_kernel<<<313, 256, 0, stream>>>(hb, pk_embout, emb_out_b, batch, pooled);
  build_z_kernel<<<136, 256, 0, stream>>>(pooled, fragl, addf, z);
  final_kernel<<<128, 256, 0, stream>>>(z, res_w1, res_b1, res_w2, res_b2, head_w, head_b,
                                        (float*)d_out);
}